// Round 7
// baseline (245.986 us; speedup 1.0000x reference)
//
#include <hip/hip_runtime.h>

// MHA fwd: B=2 S=2048 D=1024 H=16 HD=64, all-bf16 MFMA pipeline.
// r14: ATTN WITHOUT K/V LDS STAGING. Post-compaction the per-(b,h) working set
// (K 64KB + V 64KB + Q 64KB) is L2-resident and the staged loop's cost was the
// serialized barrier+vmcnt(0) drain per tile (r13 counters: occ 18%, MfmaUtil 8.9%,
// VALUBusy 26% -> latency-bound, not BW). Every LDS fragment read is 16B contiguous
// in global too (the XOR staging swizzle undoes itself): kf0=K[kk][quad*8..],
// kf1=+32, vf=V^T[d][k0+(s32*4+quad)*8..]. So: read fragments straight from global,
// delete Ks/Vs + stage + double-buffer + ALL in-loop barriers; waves run free.
// Grid back to 32x32 (64 q-rows/block, 4 blocks/CU) for TLP (r13's 512-block grid
// halved latency-hiding -> regressed).
//
// carried: r13 conv+scan single launch; r12 GEMM prefetch double-buffer; r11 MASK
// COMPACTION (map[b][j]=j-th unmasked s, tail duplicates first valid row; K/V proj
// gather rows; attn iterates ceil(cnt/64) tiles; pad tail masked via additive -1e5
// in MFMA accumulator -> exp2 underflows to +0).
//
// ws (32MB, ushort units):
//   Qh @0 (4M) | kbn @4M (4M; wob reuses after K-GEMM) | Vt @8M (4M) | ctx @12M (4M)
//   ctx region pre-attn: wqb@12M, wvb@13M, wkb@14M, map+cnt@15M (dead before attn writes ctx).
// d_out (8M ushorts scratch): qb@0 + vb@4M during QV-GEMM; then Khd@0; final fp32 overwrites.

typedef __attribute__((ext_vector_type(8))) short short8;
typedef __attribute__((ext_vector_type(4))) float f32x4;
typedef __attribute__((ext_vector_type(4))) int int32x4;

#define MFMA16(a, b, c) __builtin_amdgcn_mfma_f32_16x16x32_bf16(a, b, c, 0, 0, 0)

// async global->LDS, 16B per lane, dest = wave-uniform base + lane*16
#define GLL16(gp, lp) __builtin_amdgcn_global_load_lds( \
    (const __attribute__((address_space(1))) void*)(gp), \
    (__attribute__((address_space(3))) void*)(lp), 16, 0, 0)

static __device__ __forceinline__ unsigned short f2bf(float x) {
    unsigned int u = __float_as_uint(x);
    u = (u + 0x7fffu + ((u >> 16) & 1u)) >> 16;
    return (unsigned short)u;
}

// ---------------- fused convs + compaction scan (one launch) ----------------
// y in [0,6): fp32->bf16 convert of tensor y. y==6, x<2: per-batch compaction scan.
// map[b][j] = j-th unmasked s (j < cnt[b]); tail [cnt,2048) filled with map[b][0]
// (valid duplicate -> gathered K/V rows are always finite; attn masks j>=cnt).
__global__ __launch_bounds__(256)
void conv_scan(const float* __restrict__ s0, unsigned short* __restrict__ d0, int n0,
               const float* __restrict__ s1, unsigned short* __restrict__ d1, int n1,
               const float* __restrict__ s2, unsigned short* __restrict__ d2, int n2,
               const float* __restrict__ s3, unsigned short* __restrict__ d3, int n3,
               const float* __restrict__ s4, unsigned short* __restrict__ d4, int n4,
               const float* __restrict__ s5, unsigned short* __restrict__ d5, int n5,
               const int* __restrict__ kpm, const int* __restrict__ am,
               int* __restrict__ map, int* __restrict__ cnt)
{
    const int y = blockIdx.y;
    if (y == 6) {
        // ---- compaction scan (2 blocks) ----
        if (blockIdx.x >= 2) return;
        const int b = blockIdx.x, tid = threadIdx.x;
        const int lane = tid & 63, wave = tid >> 6;
        __shared__ int wtot[4];
        int flag[8]; int c = 0;
        const int base = b * 2048 + tid * 8;
#pragma unroll
        for (int e = 0; e < 8; ++e) {
            flag[e] = (kpm[base + e] | am[base + e]) ? 0 : 1;
            c += flag[e];
        }
        int pre = c;                      // inclusive wave prefix (shfl_up ladder)
#pragma unroll
        for (int off = 1; off < 64; off <<= 1) {
            const int t = __shfl_up(pre, off, 64);
            if (lane >= off) pre += t;
        }
        if (lane == 63) wtot[wave] = pre;
        __syncthreads();
        int woff = 0;
#pragma unroll
        for (int w = 0; w < 4; ++w) if (w < wave) woff += wtot[w];
        const int total = wtot[0] + wtot[1] + wtot[2] + wtot[3];
        if (tid == 0) cnt[b] = total;
        int off = b * 2048 + woff + (pre - c);   // exclusive prefix
        const int s0i = tid * 8;
#pragma unroll
        for (int e = 0; e < 8; ++e)
            if (flag[e]) map[off++] = s0i + e;
        __syncthreads();
        const int first = (total > 0) ? map[b * 2048] : 0;
        for (int j = total + tid; j < 2048; j += 256)
            map[b * 2048 + j] = first;
        return;
    }
    const float* s; unsigned short* d; int n;
    if (y == 0)      { s = s0; d = d0; n = n0; }
    else if (y == 1) { s = s1; d = d1; n = n1; }
    else if (y == 2) { s = s2; d = d2; n = n2; }
    else if (y == 3) { s = s3; d = d3; n = n3; }
    else if (y == 4) { s = s4; d = d4; n = n4; }
    else             { s = s5; d = d5; n = n5; }
    const int i = (blockIdx.x * 256 + threadIdx.x) * 8;
    if (i >= n) return;
    const float4 a = *(const float4*)(s + i);
    const float4 b = *(const float4*)(s + i + 4);
    ushort4 lo, hi;
    lo.x = f2bf(a.x); lo.y = f2bf(a.y); lo.z = f2bf(a.z); lo.w = f2bf(a.w);
    hi.x = f2bf(b.x); hi.y = f2bf(b.y); hi.z = f2bf(b.z); hi.w = f2bf(b.w);
    *(ushort4*)(d + i) = lo;
    *(ushort4*)(d + i + 4) = hi;
}

// single-tensor conv (Wo, after K-GEMM frees its region)
__global__ __launch_bounds__(256)
void conv_one(const float* __restrict__ s, unsigned short* __restrict__ d, int n)
{
    const int i = (blockIdx.x * 256 + threadIdx.x) * 8;
    if (i >= n) return;
    const float4 a = *(const float4*)(s + i);
    const float4 b = *(const float4*)(s + i + 4);
    ushort4 lo, hi;
    lo.x = f2bf(a.x); lo.y = f2bf(a.y); lo.z = f2bf(a.z); lo.w = f2bf(a.w);
    hi.x = f2bf(b.x); hi.y = f2bf(b.y); hi.z = f2bf(b.z); hi.w = f2bf(b.w);
    *(ushort4*)(d + i) = lo;
    *(ushort4*)(d + i + 4) = hi;
}

// ---------------- bf16 GEMM core: C[i][j] = alpha*(sum_k A[i][k] W[j][k] + bias[j]) ----------
// Tile 128x64, BK=64, double-buffered 48KB LDS, prefetch: barrier -> stage(t+1) -> compute(t).
// sub in [0,512): XCD-swizzled. LDS chunk slot(row,qc) = row*8 + (qc ^ (row&7));
// DMA source qc = (lane&7)^(lane>>3).
// GATHER: A-row index via map[b][m-local + row]; blocks beyond round_up(cnt,64) exit.
// OUT_MODE 0: fp32 [4096][1024]; 1: bf16 [B][H][S][64]; 2: bf16 [B][H][64][S] (LDS transpose)
template<int OUT_MODE, bool GATHER>
static __device__ __forceinline__
void gemm_core(int sub, const unsigned short* __restrict__ A, const unsigned short* __restrict__ Wb,
               const float* __restrict__ bias, float alpha, void* __restrict__ outp,
               unsigned short* sm, const int* __restrict__ map, const int* __restrict__ cnt)
{
    constexpr int N = 1024, K = 1024;
    const int xcd = sub & 7, loc = sub >> 3;          // loc 0..63
    const int m0 = (xcd * 4 + (loc >> 4)) * 128;      // 32 m-tiles
    const int n0 = (loc & 15) * 64;                   // 16 n-tiles

    const int tid = threadIdx.x, lane = tid & 63, wave = tid >> 6;
    const int lr = lane & 15, quad = lane >> 4;
    const int wm = (wave >> 1) * 64, wn = (wave & 1) * 32;
    const int lr3 = lane >> 3;            // 0..7
    const int qcs = (lane & 7) ^ lr3;     // swizzled source chunk index

    const int bb = m0 >> 11;              // batch (m-space is b*2048 + s)
    int arow[4];
    if constexpr (GATHER) {
        const int cntb = cnt[bb];
        int cnt64 = (cntb + 63) & ~63;
        if (cnt64 < 64) cnt64 = 64;
        if ((m0 & 2047) >= cnt64) return;             // uniform: whole block exits
#pragma unroll
        for (int n = 0; n < 4; n++) {
            const int row = (wave * 4 + n) * 8 + lr3;
            arow[n] = bb * 2048 + map[bb * 2048 + (m0 & 2047) + row];
        }
    } else {
#pragma unroll
        for (int n = 0; n < 4; n++)
            arow[n] = m0 + (wave * 4 + n) * 8 + lr3;
    }

    f32x4 acc[4][2];
#pragma unroll
    for (int mt = 0; mt < 4; mt++)
#pragma unroll
        for (int nt = 0; nt < 2; nt++) acc[mt][nt] = (f32x4){0.f, 0.f, 0.f, 0.f};

    // stage K-tile t into buffer t&1 (A: 128x64 = 16KB @ +0, B: 64x64 = 8KB @ +8192)
    auto stg = [&](int t) {
        unsigned short* Asb = sm + (t & 1) * 12288;
        unsigned short* Bsb = Asb + 8192;
        const int k0 = t * 64;
#pragma unroll
        for (int n = 0; n < 4; n++) {     // A: 1024 chunks
            const int W = wave * 4 + n;   // 0..15
            GLL16(A + (size_t)arow[n] * K + k0 + qcs * 8, Asb + W * 512);
        }
#pragma unroll
        for (int n = 0; n < 2; n++) {     // B: 512 chunks
            const int W = wave * 2 + n;   // 0..7
            const int row = W * 8 + lr3;  // 0..63
            GLL16(Wb + (size_t)(n0 + row) * K + k0 + qcs * 8, Bsb + W * 512);
        }
    };

    stg(0);

    for (int it = 0; it < 16; ++it) {
        __syncthreads();                  // drains prev-iter DMA (vmcnt(0) at barrier)
        if (it + 1 < 16) stg(it + 1);     // prefetch next tile into other buffer
        const unsigned short* Asc = sm + (it & 1) * 12288;
        const unsigned short* Bsc = Asc + 8192;
#pragma unroll
        for (int kc = 0; kc < 2; kc++) {
            short8 af[4], bfr[2];
#pragma unroll
            for (int mt = 0; mt < 4; mt++) {
                const int r = wm + mt * 16 + lr;
                af[mt] = *(const short8*)&Asc[(r * 8 + ((kc * 4 + quad) ^ (r & 7))) * 8];
            }
#pragma unroll
            for (int nt = 0; nt < 2; nt++) {
                const int r = wn + nt * 16 + lr;
                bfr[nt] = *(const short8*)&Bsc[(r * 8 + ((kc * 4 + quad) ^ (r & 7))) * 8];
            }
#pragma unroll
            for (int mt = 0; mt < 4; mt++)
#pragma unroll
                for (int nt = 0; nt < 2; nt++)
                    acc[mt][nt] = MFMA16(af[mt], bfr[nt], acc[mt][nt]);
        }
    }

    if constexpr (OUT_MODE == 2) {
        // V^T: transpose 128(s) x 64(dd) via LDS (reuse sm), coalesced stores.
        constexpr int LDT = 136;               // 272B row stride, 16B-aligned
        __syncthreads();
        unsigned short* Ts = sm;               // 64*136*2 = 17408 B <= 48KB
#pragma unroll
        for (int mt = 0; mt < 4; mt++)
#pragma unroll
            for (int nt = 0; nt < 2; nt++) {
                const int dd = wn + nt * 16 + lr;
                const int ss = wm + mt * 16 + quad * 4;
                const int j = n0 + dd;
                ushort4 tv;
                tv.x = f2bf(alpha * (acc[mt][nt][0] + bias[j]));
                tv.y = f2bf(alpha * (acc[mt][nt][1] + bias[j]));
                tv.z = f2bf(alpha * (acc[mt][nt][2] + bias[j]));
                tv.w = f2bf(alpha * (acc[mt][nt][3] + bias[j]));
                *(ushort4*)&Ts[dd * LDT + ss] = tv;
            }
        __syncthreads();
        const int b = m0 >> 11, hh = (n0 >> 6) & 15, sbase = m0 & 2047;
        const int row = tid >> 2, c4 = (tid & 3) * 32;   // row = dd 0..63
        unsigned short* dst = (unsigned short*)outp
            + (((size_t)(b * 16 + hh) * 64) + row) * 2048 + sbase + c4;
#pragma unroll
        for (int t = 0; t < 4; ++t)
            *(short8*)&dst[t * 8] = *(const short8*)&Ts[row * LDT + c4 + t * 8];
        return;
    }

#pragma unroll
    for (int mt = 0; mt < 4; mt++)
#pragma unroll
        for (int nt = 0; nt < 2; nt++)
#pragma unroll
            for (int r = 0; r < 4; r++) {
                const int i = m0 + wm + mt * 16 + quad * 4 + r;
                const int j = n0 + wn + nt * 16 + lr;
                const float val = alpha * (acc[mt][nt][r] + bias[j]);
                if constexpr (OUT_MODE == 0) {
                    ((float*)outp)[(size_t)i * N + j] = val;
                } else {
                    const int b = i >> 11, s = i & 2047, hh = j >> 6, dd = j & 63;
                    ((unsigned short*)outp)[(((size_t)(b * 16 + hh) * 2048) + s) * 64 + dd] = f2bf(val);
                }
            }
}

// fused Q+V projections: id<512 -> Q (mode 1, dense), else V (mode 2, gathered+transposed).
__global__ __launch_bounds__(256)
void gemm_qv(const unsigned short* __restrict__ qb, const unsigned short* __restrict__ wqb,
             const float* __restrict__ bq, float alpha_q, void* __restrict__ Qh,
             const unsigned short* __restrict__ vb, const unsigned short* __restrict__ wvb,
             const float* __restrict__ bv, void* __restrict__ Vt,
             const int* __restrict__ map, const int* __restrict__ cnt)
{
    __shared__ unsigned short sm[24576];
    const int id = blockIdx.x, sub = id & 511;
    if (id < 512) gemm_core<1, false>(sub, qb, wqb, bq, alpha_q, Qh, sm, nullptr, nullptr);
    else          gemm_core<2, true >(sub, vb, wvb, bv, 1.0f,   Vt, sm, map, cnt);
}

template<int OUT_MODE, bool GATHER>
__global__ __launch_bounds__(256)
void gemm_one(const unsigned short* __restrict__ A, const unsigned short* __restrict__ Wb,
              const float* __restrict__ bias, float alpha, void* __restrict__ outp,
              const int* __restrict__ map, const int* __restrict__ cnt)
{
    __shared__ unsigned short sm[24576];
    gemm_core<OUT_MODE, GATHER>(blockIdx.x, A, Wb, bias, alpha, outp, sm, map, cnt);
}

// ---------------- attention (compacted K/V, no LDS staging) ----------------
// Per block: 64 q-rows (4 waves x 16), KVBLK=64. K/V fragments read DIRECTLY from
// global (L2-resident post-compaction): kf0 = K[kk][quad*8..], kf1 = +32,
// vf = V^T[d][k0+(s32*4+quad)*8..] -- all 16B contiguous per lane. No Ks/Vs LDS,
// no double-buffer, no in-loop barriers; waves run free (4 blocks/CU TLP).
// Swapped QK^T (mfma(K,Q)): lane holds P[k=tt*16+quad*4+r][q=lr].
// Block recounts cnt from masks; iterates ceil(cnt/64) tiles; pad tail masked via
// additive -1e5 in the MFMA accumulator (exp2 -> +0).
__global__ __launch_bounds__(256)
void attn_kernel(const unsigned short* __restrict__ Qh, const unsigned short* __restrict__ Kh,
                 const unsigned short* __restrict__ Vt, const int* __restrict__ kpm,
                 const int* __restrict__ am, unsigned short* __restrict__ ctx)
{
    const int qb = blockIdx.x, bh = blockIdx.y, b = bh >> 4, h = bh & 15;
    const int q0 = qb * 64;
    const int tid = threadIdx.x, lane = tid & 63, wave = tid >> 6;
    const int lr = lane & 15, quad = lane >> 4;

    __shared__ int wred[4];

    // recount unmasked columns for this batch (matches scan's predicate)
    {
        int c = 0;
        const int mb = b * 2048 + tid * 8;
#pragma unroll
        for (int e = 0; e < 8; ++e)
            c += (kpm[mb + e] | am[mb + e]) ? 0 : 1;
#pragma unroll
        for (int off = 32; off > 0; off >>= 1)
            c += __shfl_xor(c, off, 64);
        if (lane == 0) wred[wave] = c;
    }
    __syncthreads();
    const int cntb = wred[0] + wred[1] + wred[2] + wred[3];
    const int nits = (cntb > 0) ? ((cntb + 63) >> 6) : 1;

    const unsigned short* Kbh = Kh + (size_t)bh * 2048 * 64;
    const unsigned short* Vbh = Vt + (size_t)bh * 64 * 2048;

    const unsigned short* Qbase = Qh + ((size_t)bh * 2048 + q0 + wave * 16 + lr) * 64 + quad * 8;
    const short8 qf0 = *(const short8*)Qbase;
    const short8 qf1 = *(const short8*)(Qbase + 32);

    short8 onesA;
#pragma unroll
    for (int j = 0; j < 8; j++) onesA[j] = (short)0x3F80;

    f32x4 o[4];
    f32x4 lacc = (f32x4){0.f, 0.f, 0.f, 0.f};
#pragma unroll
    for (int nt = 0; nt < 4; nt++) o[nt] = (f32x4){0.f, 0.f, 0.f, 0.f};

    const int srcA = (quad & 1) * 32 + lr;
    const int srcB = srcA + 16;

    for (int it = 0; it < nits; ++it) {
        const int k0 = it * 64;
#pragma unroll
        for (int s32 = 0; s32 < 2; ++s32) {
            unsigned int pk[2][2];
#pragma unroll
            for (int tt = 0; tt < 2; ++tt) {
                const int kk = k0 + (s32 * 2 + tt) * 16 + lr;
                const short8 kf0 = *(const short8*)&Kbh[(size_t)kk * 64 + quad * 8];
                const short8 kf1 = *(const short8*)&Kbh[(size_t)kk * 64 + quad * 8 + 32];
                f32x4 z;
                if (k0 + 64 <= cntb) {        // uniform branch: tile fully valid
                    z = (f32x4){0.f, 0.f, 0.f, 0.f};
                } else {                       // last tile: mask padded columns
                    const int jb = k0 + (s32 * 2 + tt) * 16 + quad * 4;
#pragma unroll
                    for (int r = 0; r < 4; ++r)
                        z[r] = (jb + r < cntb) ? 0.f : -1e5f;
                }
                z = MFMA16(kf0, qf0, z);
                z = MFMA16(kf1, qf1, z);
                const float p0 = __builtin_amdgcn_exp2f(z[0]);
                const float p1 = __builtin_amdgcn_exp2f(z[1]);
                const float p2 = __builtin_amdgcn_exp2f(z[2]);
                const float p3 = __builtin_amdgcn_exp2f(z[3]);
                pk[tt][0] = ((unsigned)f2bf(p1) << 16) | f2bf(p0);
                pk[tt][1] = ((unsigned)f2bf(p3) << 16) | f2bf(p2);
            }
            const int a0 = __shfl((int)pk[0][0], srcA, 64);
            const int a1 = __shfl((int)pk[0][1], srcA, 64);
            const int a2 = __shfl((int)pk[0][0], srcB, 64);
            const int a3 = __shfl((int)pk[0][1], srcB, 64);
            const int c0 = __shfl((int)pk[1][0], srcA, 64);
            const int c1 = __shfl((int)pk[1][1], srcA, 64);
            const int c2 = __shfl((int)pk[1][0], srcB, 64);
            const int c3 = __shfl((int)pk[1][1], srcB, 64);
            const bool hi = quad >= 2;
            union { int32x4 i; short8 s; } u;
            u.i = (int32x4){hi ? c0 : a0, hi ? c1 : a1, hi ? c2 : a2, hi ? c3 : a3};
            const short8 pb = u.s;

            lacc = MFMA16(onesA, pb, lacc);
#pragma unroll
            for (int nt = 0; nt < 4; ++nt) {
                const int d = nt * 16 + lr;
                const short8 vf = *(const short8*)&Vbh[(size_t)d * 2048 + k0 + (s32 * 4 + quad) * 8];
                o[nt] = MFMA16(vf, pb, o[nt]);
            }
        }
    }

    const float linv = 1.f / lacc[0];
    const int srow = q0 + wave * 16 + lr;
#pragma unroll
    for (int nt = 0; nt < 4; ++nt) {
        ushort4 pk4;
        pk4.x = f2bf(o[nt][0] * linv);
        pk4.y = f2bf(o[nt][1] * linv);
        pk4.z = f2bf(o[nt][2] * linv);
        pk4.w = f2bf(o[nt][3] * linv);
        *(ushort4*)&ctx[((size_t)(b * 2048 + srow)) * 1024 + h * 64 + nt * 16 + quad * 4] = pk4;
    }
}

extern "C" void kernel_launch(void* const* d_in, const int* in_sizes, int n_in,
                              void* d_out, int out_size, void* d_ws, size_t ws_size,
                              hipStream_t stream)
{
    const float* query = (const float*)d_in[0];
    const float* key_  = (const float*)d_in[1];
    const float* value = (const float*)d_in[2];
    const int* kpm     = (const int*)d_in[3];
    const int* am      = (const int*)d_in[4];
    const float* Wq = (const float*)d_in[6];
    const float* bq = (const float*)d_in[7];
    const float* Wk = (const float*)d_in[8];
    const float* bk = (const float*)d_in[9];
    const float* Wv = (const float*)d_in[10];
    const float* bv = (const float*)d_in[11];
    const float* Wo = (const float*)d_in[12];
    const float* bo = (const float*)d_in[13];

    unsigned short* ws16 = (unsigned short*)d_ws;
    unsigned short* Qh  = ws16;                         // 4M elems
    unsigned short* kbn = ws16 + (1u << 22);            // 4M: bf16 key input
    unsigned short* wob = ws16 + (1u << 22);            // 1M: reuses kbn after K-GEMM
    unsigned short* Vt  = ws16 + (2u << 22);            // 4M
    unsigned short* ctx = ws16 + 3 * (1u << 22);        // 4M (attn output)
    unsigned short* wqb = ctx;                          // 1M (dead before attn)
    unsigned short* wvb = ctx + (1u << 20);             // 1M
    unsigned short* wkb = ctx + (2u << 20);             // 1M
    int* map = (int*)(ctx + (3u << 20));                // 2x2048 ints (dead before attn writes ctx)
    int* cnt = map + 4096;                              // 2 ints

    unsigned short* ob  = (unsigned short*)d_out;       // 8M ushorts of scratch
    unsigned short* qb  = ob;                           // 4M
    unsigned short* vb  = ob + (1u << 22);              // 4M
    unsigned short* Khd = ob;                           // K-proj out, reuses qb after QV-GEMM

    const dim3 blk(256);
    const float alpha_q = 0.125f * 1.4426950408889634f; // fold 1/sqrt(64) and log2(e) into Q

    conv_scan<<<dim3(2048, 7), blk, 0, stream>>>(
        query, qb,  1 << 22,
        value, vb,  1 << 22,
        key_,  kbn, 1 << 22,
        Wq,    wqb, 1 << 20,
        Wv,    wvb, 1 << 20,
        Wk,    wkb, 1 << 20,
        kpm, am, map, cnt);
    gemm_qv<<<1024, blk, 0, stream>>>(qb, wqb, bq, alpha_q, (void*)Qh, vb, wvb, bv, (void*)Vt,
                                      map, cnt);
    gemm_one<1, true><<<512, blk, 0, stream>>>(kbn, wkb, bk, 1.0f, (void*)Khd, map, cnt);
    conv_one<<<dim3(512), blk, 0, stream>>>(Wo, wob, 1 << 20);
    attn_kernel<<<dim3(32, 32), blk, 0, stream>>>(Qh, Khd, Vt, kpm, am, ctx);
    gemm_one<0, false><<<512, blk, 0, stream>>>(ctx, wob, bo, 1.0f, d_out, nullptr, nullptr);
}

// Round 8
// 208.345 us; speedup vs baseline: 1.1807x; 1.1807x over previous
//
#include <hip/hip_runtime.h>

// MHA fwd: B=2 S=2048 D=1024 H=16 HD=64, all-bf16 MFMA pipeline.
// r15: RESTORE r12's staged attn (r14's no-staging variant was L2-latency-bound:
// 72.8us, MfmaUtil 5.5% -- global_load_lds prefetch WAS hiding L2 latency; direct
// per-fragment global reads put ~200cy on the dep chain). 64 q-rows/block, K/V
// double-buffered LDS, async prefetch, grid 32x(32+1): the +1 y-slice converts
// Wo->wob concurrently with attn (removes conv_one launch + bubble; wob lives in
// the dead kbn region, disjoint from attn's Qh/Khd/Vt reads and ctx writes).
//
// carried: r13 conv+scan single launch; r12 GEMM prefetch double-buffer; r11 MASK
// COMPACTION (map[b][j]=j-th unmasked s, tail duplicates first valid row; K/V proj
// gather rows; attn iterates ceil(cnt/64) tiles; pad tail masked via additive -1e5
// in MFMA accumulator -> exp2 underflows to +0).
//
// ws (32MB, ushort units):
//   Qh @0 (4M) | kbn @4M (4M; wob reuses after K-GEMM) | Vt @8M (4M) | ctx @12M (4M)
//   ctx region pre-attn: wqb@12M, wvb@13M, wkb@14M, map+cnt@15M (dead before attn writes ctx).
// d_out (8M ushorts scratch): qb@0 + vb@4M during QV-GEMM; then Khd@0; final fp32 overwrites.

typedef __attribute__((ext_vector_type(8))) short short8;
typedef __attribute__((ext_vector_type(4))) float f32x4;
typedef __attribute__((ext_vector_type(4))) int int32x4;

#define MFMA16(a, b, c) __builtin_amdgcn_mfma_f32_16x16x32_bf16(a, b, c, 0, 0, 0)

// async global->LDS, 16B per lane, dest = wave-uniform base + lane*16
#define GLL16(gp, lp) __builtin_amdgcn_global_load_lds( \
    (const __attribute__((address_space(1))) void*)(gp), \
    (__attribute__((address_space(3))) void*)(lp), 16, 0, 0)

static __device__ __forceinline__ unsigned short f2bf(float x) {
    unsigned int u = __float_as_uint(x);
    u = (u + 0x7fffu + ((u >> 16) & 1u)) >> 16;
    return (unsigned short)u;
}

// ---------------- fused convs + compaction scan (one launch) ----------------
// y in [0,6): fp32->bf16 convert of tensor y. y==6, x<2: per-batch compaction scan.
// map[b][j] = j-th unmasked s (j < cnt[b]); tail [cnt,2048) filled with map[b][0]
// (valid duplicate -> gathered K/V rows are always finite; attn masks j>=cnt).
__global__ __launch_bounds__(256)
void conv_scan(const float* __restrict__ s0, unsigned short* __restrict__ d0, int n0,
               const float* __restrict__ s1, unsigned short* __restrict__ d1, int n1,
               const float* __restrict__ s2, unsigned short* __restrict__ d2, int n2,
               const float* __restrict__ s3, unsigned short* __restrict__ d3, int n3,
               const float* __restrict__ s4, unsigned short* __restrict__ d4, int n4,
               const float* __restrict__ s5, unsigned short* __restrict__ d5, int n5,
               const int* __restrict__ kpm, const int* __restrict__ am,
               int* __restrict__ map, int* __restrict__ cnt)
{
    const int y = blockIdx.y;
    if (y == 6) {
        // ---- compaction scan (2 blocks) ----
        if (blockIdx.x >= 2) return;
        const int b = blockIdx.x, tid = threadIdx.x;
        const int lane = tid & 63, wave = tid >> 6;
        __shared__ int wtot[4];
        int flag[8]; int c = 0;
        const int base = b * 2048 + tid * 8;
#pragma unroll
        for (int e = 0; e < 8; ++e) {
            flag[e] = (kpm[base + e] | am[base + e]) ? 0 : 1;
            c += flag[e];
        }
        int pre = c;                      // inclusive wave prefix (shfl_up ladder)
#pragma unroll
        for (int off = 1; off < 64; off <<= 1) {
            const int t = __shfl_up(pre, off, 64);
            if (lane >= off) pre += t;
        }
        if (lane == 63) wtot[wave] = pre;
        __syncthreads();
        int woff = 0;
#pragma unroll
        for (int w = 0; w < 4; ++w) if (w < wave) woff += wtot[w];
        const int total = wtot[0] + wtot[1] + wtot[2] + wtot[3];
        if (tid == 0) cnt[b] = total;
        int off = b * 2048 + woff + (pre - c);   // exclusive prefix
        const int s0i = tid * 8;
#pragma unroll
        for (int e = 0; e < 8; ++e)
            if (flag[e]) map[off++] = s0i + e;
        __syncthreads();
        const int first = (total > 0) ? map[b * 2048] : 0;
        for (int j = total + tid; j < 2048; j += 256)
            map[b * 2048 + j] = first;
        return;
    }
    const float* s; unsigned short* d; int n;
    if (y == 0)      { s = s0; d = d0; n = n0; }
    else if (y == 1) { s = s1; d = d1; n = n1; }
    else if (y == 2) { s = s2; d = d2; n = n2; }
    else if (y == 3) { s = s3; d = d3; n = n3; }
    else if (y == 4) { s = s4; d = d4; n = n4; }
    else             { s = s5; d = d5; n = n5; }
    const int i = (blockIdx.x * 256 + threadIdx.x) * 8;
    if (i >= n) return;
    const float4 a = *(const float4*)(s + i);
    const float4 b = *(const float4*)(s + i + 4);
    ushort4 lo, hi;
    lo.x = f2bf(a.x); lo.y = f2bf(a.y); lo.z = f2bf(a.z); lo.w = f2bf(a.w);
    hi.x = f2bf(b.x); hi.y = f2bf(b.y); hi.z = f2bf(b.z); hi.w = f2bf(b.w);
    *(ushort4*)(d + i) = lo;
    *(ushort4*)(d + i + 4) = hi;
}

// ---------------- bf16 GEMM core: C[i][j] = alpha*(sum_k A[i][k] W[j][k] + bias[j]) ----------
// Tile 128x64, BK=64, double-buffered 48KB LDS, prefetch: barrier -> stage(t+1) -> compute(t).
// sub in [0,512): XCD-swizzled. LDS chunk slot(row,qc) = row*8 + (qc ^ (row&7));
// DMA source qc = (lane&7)^(lane>>3).
// GATHER: A-row index via map[b][m-local + row]; blocks beyond round_up(cnt,64) exit.
// OUT_MODE 0: fp32 [4096][1024]; 1: bf16 [B][H][S][64]; 2: bf16 [B][H][64][S] (LDS transpose)
template<int OUT_MODE, bool GATHER>
static __device__ __forceinline__
void gemm_core(int sub, const unsigned short* __restrict__ A, const unsigned short* __restrict__ Wb,
               const float* __restrict__ bias, float alpha, void* __restrict__ outp,
               unsigned short* sm, const int* __restrict__ map, const int* __restrict__ cnt)
{
    constexpr int N = 1024, K = 1024;
    const int xcd = sub & 7, loc = sub >> 3;          // loc 0..63
    const int m0 = (xcd * 4 + (loc >> 4)) * 128;      // 32 m-tiles
    const int n0 = (loc & 15) * 64;                   // 16 n-tiles

    const int tid = threadIdx.x, lane = tid & 63, wave = tid >> 6;
    const int lr = lane & 15, quad = lane >> 4;
    const int wm = (wave >> 1) * 64, wn = (wave & 1) * 32;
    const int lr3 = lane >> 3;            // 0..7
    const int qcs = (lane & 7) ^ lr3;     // swizzled source chunk index

    const int bb = m0 >> 11;              // batch (m-space is b*2048 + s)
    int arow[4];
    if constexpr (GATHER) {
        const int cntb = cnt[bb];
        int cnt64 = (cntb + 63) & ~63;
        if (cnt64 < 64) cnt64 = 64;
        if ((m0 & 2047) >= cnt64) return;             // uniform: whole block exits
#pragma unroll
        for (int n = 0; n < 4; n++) {
            const int row = (wave * 4 + n) * 8 + lr3;
            arow[n] = bb * 2048 + map[bb * 2048 + (m0 & 2047) + row];
        }
    } else {
#pragma unroll
        for (int n = 0; n < 4; n++)
            arow[n] = m0 + (wave * 4 + n) * 8 + lr3;
    }

    f32x4 acc[4][2];
#pragma unroll
    for (int mt = 0; mt < 4; mt++)
#pragma unroll
        for (int nt = 0; nt < 2; nt++) acc[mt][nt] = (f32x4){0.f, 0.f, 0.f, 0.f};

    // stage K-tile t into buffer t&1 (A: 128x64 = 16KB @ +0, B: 64x64 = 8KB @ +8192)
    auto stg = [&](int t) {
        unsigned short* Asb = sm + (t & 1) * 12288;
        unsigned short* Bsb = Asb + 8192;
        const int k0 = t * 64;
#pragma unroll
        for (int n = 0; n < 4; n++) {     // A: 1024 chunks
            const int W = wave * 4 + n;   // 0..15
            GLL16(A + (size_t)arow[n] * K + k0 + qcs * 8, Asb + W * 512);
        }
#pragma unroll
        for (int n = 0; n < 2; n++) {     // B: 512 chunks
            const int W = wave * 2 + n;   // 0..7
            const int row = W * 8 + lr3;  // 0..63
            GLL16(Wb + (size_t)(n0 + row) * K + k0 + qcs * 8, Bsb + W * 512);
        }
    };

    stg(0);

    for (int it = 0; it < 16; ++it) {
        __syncthreads();                  // drains prev-iter DMA (vmcnt(0) at barrier)
        if (it + 1 < 16) stg(it + 1);     // prefetch next tile into other buffer
        const unsigned short* Asc = sm + (it & 1) * 12288;
        const unsigned short* Bsc = Asc + 8192;
#pragma unroll
        for (int kc = 0; kc < 2; kc++) {
            short8 af[4], bfr[2];
#pragma unroll
            for (int mt = 0; mt < 4; mt++) {
                const int r = wm + mt * 16 + lr;
                af[mt] = *(const short8*)&Asc[(r * 8 + ((kc * 4 + quad) ^ (r & 7))) * 8];
            }
#pragma unroll
            for (int nt = 0; nt < 2; nt++) {
                const int r = wn + nt * 16 + lr;
                bfr[nt] = *(const short8*)&Bsc[(r * 8 + ((kc * 4 + quad) ^ (r & 7))) * 8];
            }
#pragma unroll
            for (int mt = 0; mt < 4; mt++)
#pragma unroll
                for (int nt = 0; nt < 2; nt++)
                    acc[mt][nt] = MFMA16(af[mt], bfr[nt], acc[mt][nt]);
        }
    }

    if constexpr (OUT_MODE == 2) {
        // V^T: transpose 128(s) x 64(dd) via LDS (reuse sm), coalesced stores.
        constexpr int LDT = 136;               // 272B row stride, 16B-aligned
        __syncthreads();
        unsigned short* Ts = sm;               // 64*136*2 = 17408 B <= 48KB
#pragma unroll
        for (int mt = 0; mt < 4; mt++)
#pragma unroll
            for (int nt = 0; nt < 2; nt++) {
                const int dd = wn + nt * 16 + lr;
                const int ss = wm + mt * 16 + quad * 4;
                const int j = n0 + dd;
                ushort4 tv;
                tv.x = f2bf(alpha * (acc[mt][nt][0] + bias[j]));
                tv.y = f2bf(alpha * (acc[mt][nt][1] + bias[j]));
                tv.z = f2bf(alpha * (acc[mt][nt][2] + bias[j]));
                tv.w = f2bf(alpha * (acc[mt][nt][3] + bias[j]));
                *(ushort4*)&Ts[dd * LDT + ss] = tv;
            }
        __syncthreads();
        const int b = m0 >> 11, hh = (n0 >> 6) & 15, sbase = m0 & 2047;
        const int row = tid >> 2, c4 = (tid & 3) * 32;   // row = dd 0..63
        unsigned short* dst = (unsigned short*)outp
            + (((size_t)(b * 16 + hh) * 64) + row) * 2048 + sbase + c4;
#pragma unroll
        for (int t = 0; t < 4; ++t)
            *(short8*)&dst[t * 8] = *(const short8*)&Ts[row * LDT + c4 + t * 8];
        return;
    }

#pragma unroll
    for (int mt = 0; mt < 4; mt++)
#pragma unroll
        for (int nt = 0; nt < 2; nt++)
#pragma unroll
            for (int r = 0; r < 4; r++) {
                const int i = m0 + wm + mt * 16 + quad * 4 + r;
                const int j = n0 + wn + nt * 16 + lr;
                const float val = alpha * (acc[mt][nt][r] + bias[j]);
                if constexpr (OUT_MODE == 0) {
                    ((float*)outp)[(size_t)i * N + j] = val;
                } else {
                    const int b = i >> 11, s = i & 2047, hh = j >> 6, dd = j & 63;
                    ((unsigned short*)outp)[(((size_t)(b * 16 + hh) * 2048) + s) * 64 + dd] = f2bf(val);
                }
            }
}

// fused Q+V projections: id<512 -> Q (mode 1, dense), else V (mode 2, gathered+transposed).
__global__ __launch_bounds__(256)
void gemm_qv(const unsigned short* __restrict__ qb, const unsigned short* __restrict__ wqb,
             const float* __restrict__ bq, float alpha_q, void* __restrict__ Qh,
             const unsigned short* __restrict__ vb, const unsigned short* __restrict__ wvb,
             const float* __restrict__ bv, void* __restrict__ Vt,
             const int* __restrict__ map, const int* __restrict__ cnt)
{
    __shared__ unsigned short sm[24576];
    const int id = blockIdx.x, sub = id & 511;
    if (id < 512) gemm_core<1, false>(sub, qb, wqb, bq, alpha_q, Qh, sm, nullptr, nullptr);
    else          gemm_core<2, true >(sub, vb, wvb, bv, 1.0f,   Vt, sm, map, cnt);
}

template<int OUT_MODE, bool GATHER>
__global__ __launch_bounds__(256)
void gemm_one(const unsigned short* __restrict__ A, const unsigned short* __restrict__ Wb,
              const float* __restrict__ bias, float alpha, void* __restrict__ outp,
              const int* __restrict__ map, const int* __restrict__ cnt)
{
    __shared__ unsigned short sm[24576];
    gemm_core<OUT_MODE, GATHER>(blockIdx.x, A, Wb, bias, alpha, outp, sm, map, cnt);
}

// ---------------- attention (compacted K/V, staged; + fused Wo conversion) ----------------
// bh < 32: per block 64 q-rows (4 waves x 16), KVBLK=64, K/V double-buffered in LDS
// with async global_load_lds prefetch (hides L2 latency -- r14 proved direct global
// fragment reads are latency-bound). Swapped QK^T (mfma(K,Q)): lane holds
// P[k=tt*16+quad*4+r][q=lr]. Block recounts cnt from masks; iterates ceil(cnt/64)
// tiles; pad tail masked via additive -1e5 in MFMA accumulator (exp2 -> +0).
// bh == 32: 32 blocks convert Wo (fp32->bf16, 1M elems) into wob concurrently.
__global__ __launch_bounds__(256)
void attn_kernel(const unsigned short* __restrict__ Qh, const unsigned short* __restrict__ Kh,
                 const unsigned short* __restrict__ Vt, const int* __restrict__ kpm,
                 const int* __restrict__ am, unsigned short* __restrict__ ctx,
                 const float* __restrict__ Wo, unsigned short* __restrict__ wob)
{
    const int bh = blockIdx.y;
    const int tid = threadIdx.x;
    if (bh >= 32) {
        // ---- Wo conversion: 32 blocks x 16 sweeps x 2048 elems ----
        const int base = (blockIdx.x * 256 + tid) * 8;   // 0..65535 step 8
        for (int i = base; i < (1 << 20); i += 32 * 256 * 8) {
            const float4 a = *(const float4*)(Wo + i);
            const float4 b = *(const float4*)(Wo + i + 4);
            ushort4 lo, hi;
            lo.x = f2bf(a.x); lo.y = f2bf(a.y); lo.z = f2bf(a.z); lo.w = f2bf(a.w);
            hi.x = f2bf(b.x); hi.y = f2bf(b.y); hi.z = f2bf(b.z); hi.w = f2bf(b.w);
            *(ushort4*)(wob + i) = lo;
            *(ushort4*)(wob + i + 4) = hi;
        }
        return;
    }

    const int qb = blockIdx.x, b = bh >> 4, h = bh & 15;
    const int q0 = qb * 64;
    const int lane = tid & 63, wave = tid >> 6;
    const int lr = lane & 15, quad = lane >> 4;

    __shared__ unsigned short Ks[2][64 * 64];
    __shared__ unsigned short Vs[2][64 * 64];
    __shared__ int wred[4];

    // recount unmasked columns for this batch (matches scan's predicate)
    {
        int c = 0;
        const int mb = b * 2048 + tid * 8;
#pragma unroll
        for (int e = 0; e < 8; ++e)
            c += (kpm[mb + e] | am[mb + e]) ? 0 : 1;
#pragma unroll
        for (int off = 32; off > 0; off >>= 1)
            c += __shfl_xor(c, off, 64);
        if (lane == 0) wred[wave] = c;
    }
    __syncthreads();
    const int cntb = wred[0] + wred[1] + wred[2] + wred[3];
    const int nits = (cntb > 0) ? ((cntb + 63) >> 6) : 1;

    const unsigned short* Kbh = Kh + (size_t)bh * 2048 * 64;
    const unsigned short* Vbh = Vt + (size_t)bh * 64 * 2048;

    const int lr3 = lane >> 3;
    const int qcs = (lane & 7) ^ lr3;

    auto stage = [&](int buf, int k0) {
#pragma unroll
        for (int n = 0; n < 2; ++n) {
            const int W = wave + n * 4;
            const int r = W * 8 + lr3;
            GLL16(Kbh + (size_t)(k0 + r) * 64 + qcs * 8, &Ks[buf][W * 512]);
            GLL16(Vbh + (size_t)r * 2048 + k0 + qcs * 8, &Vs[buf][W * 512]);
        }
    };

    const unsigned short* Qbase = Qh + ((size_t)bh * 2048 + q0 + wave * 16 + lr) * 64 + quad * 8;
    const short8 qf0 = *(const short8*)Qbase;
    const short8 qf1 = *(const short8*)(Qbase + 32);

    short8 onesA;
#pragma unroll
    for (int j = 0; j < 8; j++) onesA[j] = (short)0x3F80;

    f32x4 o[4];
    f32x4 lacc = (f32x4){0.f, 0.f, 0.f, 0.f};
#pragma unroll
    for (int nt = 0; nt < 4; nt++) o[nt] = (f32x4){0.f, 0.f, 0.f, 0.f};

    const int srcA = (quad & 1) * 32 + lr;
    const int srcB = srcA + 16;

    // Precompute swizzled LDS fragment offsets (loop-invariant; keep in VGPRs).
    int koff[2][2][2], voff[2][4];
#pragma unroll
    for (int s32 = 0; s32 < 2; ++s32) {
#pragma unroll
        for (int tt = 0; tt < 2; ++tt) {
            const int kk = (s32 * 2 + tt) * 16 + lr;
            koff[s32][tt][0] = (kk * 8 + (quad ^ (kk & 7))) * 8;
            koff[s32][tt][1] = (kk * 8 + ((quad + 4) ^ (kk & 7))) * 8;
        }
#pragma unroll
        for (int nt = 0; nt < 4; ++nt) {
            const int d = nt * 16 + lr;
            const int qc = s32 * 4 + quad;
            voff[s32][nt] = (d * 8 + (qc ^ (d & 7))) * 8;
        }
    }

    auto tile = [&](const unsigned short* __restrict__ Kb,
                    const unsigned short* __restrict__ Vb, int k0) {
#pragma unroll
        for (int s32 = 0; s32 < 2; ++s32) {
            unsigned int pk[2][2];
#pragma unroll
            for (int tt = 0; tt < 2; ++tt) {
                const short8 kf0 = *(const short8*)&Kb[koff[s32][tt][0]];
                const short8 kf1 = *(const short8*)&Kb[koff[s32][tt][1]];
                f32x4 z;
                if (k0 + 64 <= cntb) {        // uniform branch: tile fully valid
                    z = (f32x4){0.f, 0.f, 0.f, 0.f};
                } else {                       // last tile: mask padded columns
                    const int jb = k0 + (s32 * 2 + tt) * 16 + quad * 4;
#pragma unroll
                    for (int r = 0; r < 4; ++r)
                        z[r] = (jb + r < cntb) ? 0.f : -1e5f;
                }
                z = MFMA16(kf0, qf0, z);
                z = MFMA16(kf1, qf1, z);
                const float p0 = __builtin_amdgcn_exp2f(z[0]);
                const float p1 = __builtin_amdgcn_exp2f(z[1]);
                const float p2 = __builtin_amdgcn_exp2f(z[2]);
                const float p3 = __builtin_amdgcn_exp2f(z[3]);
                pk[tt][0] = ((unsigned)f2bf(p1) << 16) | f2bf(p0);
                pk[tt][1] = ((unsigned)f2bf(p3) << 16) | f2bf(p2);
            }
            const int a0 = __shfl((int)pk[0][0], srcA, 64);
            const int a1 = __shfl((int)pk[0][1], srcA, 64);
            const int a2 = __shfl((int)pk[0][0], srcB, 64);
            const int a3 = __shfl((int)pk[0][1], srcB, 64);
            const int c0 = __shfl((int)pk[1][0], srcA, 64);
            const int c1 = __shfl((int)pk[1][1], srcA, 64);
            const int c2 = __shfl((int)pk[1][0], srcB, 64);
            const int c3 = __shfl((int)pk[1][1], srcB, 64);
            const bool hi = quad >= 2;
            union { int32x4 i; short8 s; } u;
            u.i = (int32x4){hi ? c0 : a0, hi ? c1 : a1, hi ? c2 : a2, hi ? c3 : a3};
            const short8 pb = u.s;

            lacc = MFMA16(onesA, pb, lacc);
#pragma unroll
            for (int nt = 0; nt < 4; ++nt) {
                const short8 vf = *(const short8*)&Vb[voff[s32][nt]];
                o[nt] = MFMA16(vf, pb, o[nt]);
            }
        }
    };

    stage(0, 0);

    for (int it = 0; it < nits; ++it) {
        __syncthreads();
        if (it + 1 < nits) stage((it + 1) & 1, (it + 1) * 64);
        // duplicate body per buffer so LDS base is a compile-time immediate
        if (it & 1) tile(Ks[1], Vs[1], it * 64);
        else        tile(Ks[0], Vs[0], it * 64);
    }

    const float linv = 1.f / lacc[0];
    const int srow = q0 + wave * 16 + lr;
#pragma unroll
    for (int nt = 0; nt < 4; ++nt) {
        ushort4 pk4;
        pk4.x = f2bf(o[nt][0] * linv);
        pk4.y = f2bf(o[nt][1] * linv);
        pk4.z = f2bf(o[nt][2] * linv);
        pk4.w = f2bf(o[nt][3] * linv);
        *(ushort4*)&ctx[((size_t)(b * 2048 + srow)) * 1024 + h * 64 + nt * 16 + quad * 4] = pk4;
    }
}

extern "C" void kernel_launch(void* const* d_in, const int* in_sizes, int n_in,
                              void* d_out, int out_size, void* d_ws, size_t ws_size,
                              hipStream_t stream)
{
    const float* query = (const float*)d_in[0];
    const float* key_  = (const float*)d_in[1];
    const float* value = (const float*)d_in[2];
    const int* kpm     = (const int*)d_in[3];
    const int* am      = (const int*)d_in[4];
    const float* Wq = (const float*)d_in[6];
    const float* bq = (const float*)d_in[7];
    const float* Wk = (const float*)d_in[8];
    const float* bk = (const float*)d_in[9];
    const float* Wv = (const float*)d_in[10];
    const float* bv = (const float*)d_in[11];
    const float* Wo = (const float*)d_in[12];
    const float* bo = (const float*)d_in[13];

    unsigned short* ws16 = (unsigned short*)d_ws;
    unsigned short* Qh  = ws16;                         // 4M elems
    unsigned short* kbn = ws16 + (1u << 22);            // 4M: bf16 key input
    unsigned short* wob = ws16 + (1u << 22);            // 1M: reuses kbn after K-GEMM
    unsigned short* Vt  = ws16 + (2u << 22);            // 4M
    unsigned short* ctx = ws16 + 3 * (1u << 22);        // 4M (attn output)
    unsigned short* wqb = ctx;                          // 1M (dead before attn)
    unsigned short* wvb = ctx + (1u << 20);             // 1M
    unsigned short* wkb = ctx + (2u << 20);             // 1M
    int* map = (int*)(ctx + (3u << 20));                // 2x2048 ints (dead before attn writes ctx)
    int* cnt = map + 4096;                              // 2 ints

    unsigned short* ob  = (unsigned short*)d_out;       // 8M ushorts of scratch
    unsigned short* qb  = ob;                           // 4M
    unsigned short* vb  = ob + (1u << 22);              // 4M
    unsigned short* Khd = ob;                           // K-proj out, reuses qb after QV-GEMM

    const dim3 blk(256);
    const float alpha_q = 0.125f * 1.4426950408889634f; // fold 1/sqrt(64) and log2(e) into Q

    conv_scan<<<dim3(2048, 7), blk, 0, stream>>>(
        query, qb,  1 << 22,
        value, vb,  1 << 22,
        key_,  kbn, 1 << 22,
        Wq,    wqb, 1 << 20,
        Wv,    wvb, 1 << 20,
        Wk,    wkb, 1 << 20,
        kpm, am, map, cnt);
    gemm_qv<<<1024, blk, 0, stream>>>(qb, wqb, bq, alpha_q, (void*)Qh, vb, wvb, bv, (void*)Vt,
                                      map, cnt);
    gemm_one<1, true><<<512, blk, 0, stream>>>(kbn, wkb, bk, 1.0f, (void*)Khd, map, cnt);
    attn_kernel<<<dim3(32, 33), blk, 0, stream>>>(Qh, Khd, Vt, kpm, am, ctx, Wo, wob);
    gemm_one<0, false><<<512, blk, 0, stream>>>(ctx, wob, bo, 1.0f, d_out, nullptr, nullptr);
}

// Round 9
// 198.377 us; speedup vs baseline: 1.2400x; 1.0502x over previous
//
#include <hip/hip_runtime.h>

// MHA fwd: B=2 S=2048 D=1024 H=16 HD=64, all-bf16 MFMA pipeline.
// r16: MERGE ALL THREE PROJECTION GEMMs into one 1536-block launch (Q dense,
// V gathered+transposed, K gathered). r15's standalone K-GEMM had only ~128 live
// blocks of 512 (compaction exit) = 0.5 blocks/CU for a whole dispatch + bubble.
// Merged: live blocks = 512(Q)+128(V)+128(K) ~= 768 = the 3-block/CU LDS cap ->
// one fully-resident wave, dead blocks exit instantly and backfill.
// Race fix: K output (Khd) moves OFF d_out (where it collided with Q's input qb)
// to ws+32MB -- the harness fills show ws is 256MB; gated on ws_size >= 40MB with
// the exact r15 serialized schedule as fallback.
//
// carried: r15 attn (staged dbuf + async global_load_lds prefetch -- r14 proved
// unstaged is L2-latency-bound; 64 q-rows/block; Wo conversion fused as grid y==32);
// r13 conv+scan single launch; r12 GEMM prefetch dbuf; r11 MASK COMPACTION
// (map[b][j]=j-th unmasked s, tail duplicates first valid row; pad tail masked via
// additive -1e5 in MFMA accumulator -> exp2 underflows to +0).
//
// ws layout (ushort units): Qh @0 (4M) | kbn @4M (4M; wob reuses after proj-GEMMs) |
//   Vt @8M (4M) | ctx @12M (4M; pre-attn: wqb/wvb/wkb/map+cnt) | Khd2 @16M (4M, big-ws only)
// d_out (8M ushorts scratch): qb@0 + vb@4M during proj-GEMMs; final fp32 overwrites.

typedef __attribute__((ext_vector_type(8))) short short8;
typedef __attribute__((ext_vector_type(4))) float f32x4;
typedef __attribute__((ext_vector_type(4))) int int32x4;

#define MFMA16(a, b, c) __builtin_amdgcn_mfma_f32_16x16x32_bf16(a, b, c, 0, 0, 0)

// async global->LDS, 16B per lane, dest = wave-uniform base + lane*16
#define GLL16(gp, lp) __builtin_amdgcn_global_load_lds( \
    (const __attribute__((address_space(1))) void*)(gp), \
    (__attribute__((address_space(3))) void*)(lp), 16, 0, 0)

static __device__ __forceinline__ unsigned short f2bf(float x) {
    unsigned int u = __float_as_uint(x);
    u = (u + 0x7fffu + ((u >> 16) & 1u)) >> 16;
    return (unsigned short)u;
}

// ---------------- fused convs + compaction scan (one launch) ----------------
// y in [0,6): fp32->bf16 convert of tensor y. y==6, x<2: per-batch compaction scan.
// map[b][j] = j-th unmasked s (j < cnt[b]); tail [cnt,2048) filled with map[b][0]
// (valid duplicate -> gathered K/V rows are always finite; attn masks j>=cnt).
__global__ __launch_bounds__(256)
void conv_scan(const float* __restrict__ s0, unsigned short* __restrict__ d0, int n0,
               const float* __restrict__ s1, unsigned short* __restrict__ d1, int n1,
               const float* __restrict__ s2, unsigned short* __restrict__ d2, int n2,
               const float* __restrict__ s3, unsigned short* __restrict__ d3, int n3,
               const float* __restrict__ s4, unsigned short* __restrict__ d4, int n4,
               const float* __restrict__ s5, unsigned short* __restrict__ d5, int n5,
               const int* __restrict__ kpm, const int* __restrict__ am,
               int* __restrict__ map, int* __restrict__ cnt)
{
    const int y = blockIdx.y;
    if (y == 6) {
        // ---- compaction scan (2 blocks) ----
        if (blockIdx.x >= 2) return;
        const int b = blockIdx.x, tid = threadIdx.x;
        const int lane = tid & 63, wave = tid >> 6;
        __shared__ int wtot[4];
        int flag[8]; int c = 0;
        const int base = b * 2048 + tid * 8;
#pragma unroll
        for (int e = 0; e < 8; ++e) {
            flag[e] = (kpm[base + e] | am[base + e]) ? 0 : 1;
            c += flag[e];
        }
        int pre = c;                      // inclusive wave prefix (shfl_up ladder)
#pragma unroll
        for (int off = 1; off < 64; off <<= 1) {
            const int t = __shfl_up(pre, off, 64);
            if (lane >= off) pre += t;
        }
        if (lane == 63) wtot[wave] = pre;
        __syncthreads();
        int woff = 0;
#pragma unroll
        for (int w = 0; w < 4; ++w) if (w < wave) woff += wtot[w];
        const int total = wtot[0] + wtot[1] + wtot[2] + wtot[3];
        if (tid == 0) cnt[b] = total;
        int off = b * 2048 + woff + (pre - c);   // exclusive prefix
        const int s0i = tid * 8;
#pragma unroll
        for (int e = 0; e < 8; ++e)
            if (flag[e]) map[off++] = s0i + e;
        __syncthreads();
        const int first = (total > 0) ? map[b * 2048] : 0;
        for (int j = total + tid; j < 2048; j += 256)
            map[b * 2048 + j] = first;
        return;
    }
    const float* s; unsigned short* d; int n;
    if (y == 0)      { s = s0; d = d0; n = n0; }
    else if (y == 1) { s = s1; d = d1; n = n1; }
    else if (y == 2) { s = s2; d = d2; n = n2; }
    else if (y == 3) { s = s3; d = d3; n = n3; }
    else if (y == 4) { s = s4; d = d4; n = n4; }
    else             { s = s5; d = d5; n = n5; }
    const int i = (blockIdx.x * 256 + threadIdx.x) * 8;
    if (i >= n) return;
    const float4 a = *(const float4*)(s + i);
    const float4 b = *(const float4*)(s + i + 4);
    ushort4 lo, hi;
    lo.x = f2bf(a.x); lo.y = f2bf(a.y); lo.z = f2bf(a.z); lo.w = f2bf(a.w);
    hi.x = f2bf(b.x); hi.y = f2bf(b.y); hi.z = f2bf(b.z); hi.w = f2bf(b.w);
    *(ushort4*)(d + i) = lo;
    *(ushort4*)(d + i + 4) = hi;
}

// ---------------- bf16 GEMM core: C[i][j] = alpha*(sum_k A[i][k] W[j][k] + bias[j]) ----------
// Tile 128x64, BK=64, double-buffered 48KB LDS, prefetch: barrier -> stage(t+1) -> compute(t).
// sub in [0,512): XCD-swizzled. LDS chunk slot(row,qc) = row*8 + (qc ^ (row&7));
// DMA source qc = (lane&7)^(lane>>3).
// GATHER: A-row index via map[b][m-local + row]; blocks beyond round_up(cnt,64) exit.
// OUT_MODE 0: fp32 [4096][1024]; 1: bf16 [B][H][S][64]; 2: bf16 [B][H][64][S] (LDS transpose)
template<int OUT_MODE, bool GATHER>
static __device__ __forceinline__
void gemm_core(int sub, const unsigned short* __restrict__ A, const unsigned short* __restrict__ Wb,
               const float* __restrict__ bias, float alpha, void* __restrict__ outp,
               unsigned short* sm, const int* __restrict__ map, const int* __restrict__ cnt)
{
    constexpr int N = 1024, K = 1024;
    const int xcd = sub & 7, loc = sub >> 3;          // loc 0..63
    const int m0 = (xcd * 4 + (loc >> 4)) * 128;      // 32 m-tiles
    const int n0 = (loc & 15) * 64;                   // 16 n-tiles

    const int tid = threadIdx.x, lane = tid & 63, wave = tid >> 6;
    const int lr = lane & 15, quad = lane >> 4;
    const int wm = (wave >> 1) * 64, wn = (wave & 1) * 32;
    const int lr3 = lane >> 3;            // 0..7
    const int qcs = (lane & 7) ^ lr3;     // swizzled source chunk index

    const int bb = m0 >> 11;              // batch (m-space is b*2048 + s)
    int arow[4];
    if constexpr (GATHER) {
        const int cntb = cnt[bb];
        int cnt64 = (cntb + 63) & ~63;
        if (cnt64 < 64) cnt64 = 64;
        if ((m0 & 2047) >= cnt64) return;             // uniform: whole block exits
#pragma unroll
        for (int n = 0; n < 4; n++) {
            const int row = (wave * 4 + n) * 8 + lr3;
            arow[n] = bb * 2048 + map[bb * 2048 + (m0 & 2047) + row];
        }
    } else {
#pragma unroll
        for (int n = 0; n < 4; n++)
            arow[n] = m0 + (wave * 4 + n) * 8 + lr3;
    }

    f32x4 acc[4][2];
#pragma unroll
    for (int mt = 0; mt < 4; mt++)
#pragma unroll
        for (int nt = 0; nt < 2; nt++) acc[mt][nt] = (f32x4){0.f, 0.f, 0.f, 0.f};

    // stage K-tile t into buffer t&1 (A: 128x64 = 16KB @ +0, B: 64x64 = 8KB @ +8192)
    auto stg = [&](int t) {
        unsigned short* Asb = sm + (t & 1) * 12288;
        unsigned short* Bsb = Asb + 8192;
        const int k0 = t * 64;
#pragma unroll
        for (int n = 0; n < 4; n++) {     // A: 1024 chunks
            const int W = wave * 4 + n;   // 0..15
            GLL16(A + (size_t)arow[n] * K + k0 + qcs * 8, Asb + W * 512);
        }
#pragma unroll
        for (int n = 0; n < 2; n++) {     // B: 512 chunks
            const int W = wave * 2 + n;   // 0..7
            const int row = W * 8 + lr3;  // 0..63
            GLL16(Wb + (size_t)(n0 + row) * K + k0 + qcs * 8, Bsb + W * 512);
        }
    };

    stg(0);

    for (int it = 0; it < 16; ++it) {
        __syncthreads();                  // drains prev-iter DMA (vmcnt(0) at barrier)
        if (it + 1 < 16) stg(it + 1);     // prefetch next tile into other buffer
        const unsigned short* Asc = sm + (it & 1) * 12288;
        const unsigned short* Bsc = Asc + 8192;
#pragma unroll
        for (int kc = 0; kc < 2; kc++) {
            short8 af[4], bfr[2];
#pragma unroll
            for (int mt = 0; mt < 4; mt++) {
                const int r = wm + mt * 16 + lr;
                af[mt] = *(const short8*)&Asc[(r * 8 + ((kc * 4 + quad) ^ (r & 7))) * 8];
            }
#pragma unroll
            for (int nt = 0; nt < 2; nt++) {
                const int r = wn + nt * 16 + lr;
                bfr[nt] = *(const short8*)&Bsc[(r * 8 + ((kc * 4 + quad) ^ (r & 7))) * 8];
            }
#pragma unroll
            for (int mt = 0; mt < 4; mt++)
#pragma unroll
                for (int nt = 0; nt < 2; nt++)
                    acc[mt][nt] = MFMA16(af[mt], bfr[nt], acc[mt][nt]);
        }
    }

    if constexpr (OUT_MODE == 2) {
        // V^T: transpose 128(s) x 64(dd) via LDS (reuse sm), coalesced stores.
        constexpr int LDT = 136;               // 272B row stride, 16B-aligned
        __syncthreads();
        unsigned short* Ts = sm;               // 64*136*2 = 17408 B <= 48KB
#pragma unroll
        for (int mt = 0; mt < 4; mt++)
#pragma unroll
            for (int nt = 0; nt < 2; nt++) {
                const int dd = wn + nt * 16 + lr;
                const int ss = wm + mt * 16 + quad * 4;
                const int j = n0 + dd;
                ushort4 tv;
                tv.x = f2bf(alpha * (acc[mt][nt][0] + bias[j]));
                tv.y = f2bf(alpha * (acc[mt][nt][1] + bias[j]));
                tv.z = f2bf(alpha * (acc[mt][nt][2] + bias[j]));
                tv.w = f2bf(alpha * (acc[mt][nt][3] + bias[j]));
                *(ushort4*)&Ts[dd * LDT + ss] = tv;
            }
        __syncthreads();
        const int b = m0 >> 11, hh = (n0 >> 6) & 15, sbase = m0 & 2047;
        const int row = tid >> 2, c4 = (tid & 3) * 32;   // row = dd 0..63
        unsigned short* dst = (unsigned short*)outp
            + (((size_t)(b * 16 + hh) * 64) + row) * 2048 + sbase + c4;
#pragma unroll
        for (int t = 0; t < 4; ++t)
            *(short8*)&dst[t * 8] = *(const short8*)&Ts[row * LDT + c4 + t * 8];
        return;
    }

#pragma unroll
    for (int mt = 0; mt < 4; mt++)
#pragma unroll
        for (int nt = 0; nt < 2; nt++)
#pragma unroll
            for (int r = 0; r < 4; r++) {
                const int i = m0 + wm + mt * 16 + quad * 4 + r;
                const int j = n0 + wn + nt * 16 + lr;
                const float val = alpha * (acc[mt][nt][r] + bias[j]);
                if constexpr (OUT_MODE == 0) {
                    ((float*)outp)[(size_t)i * N + j] = val;
                } else {
                    const int b = i >> 11, s = i & 2047, hh = j >> 6, dd = j & 63;
                    ((unsigned short*)outp)[(((size_t)(b * 16 + hh) * 2048) + s) * 64 + dd] = f2bf(val);
                }
            }
}

// merged projections (big-ws path): id<512 Q (dense), 512..1023 V (gather+transpose),
// 1024..1535 K (gather). All read only conv_scan outputs; outputs disjoint.
__global__ __launch_bounds__(256)
void gemm_qvk(const unsigned short* __restrict__ qb, const unsigned short* __restrict__ wqb,
              const float* __restrict__ bq, float alpha_q, void* __restrict__ Qh,
              const unsigned short* __restrict__ vb, const unsigned short* __restrict__ wvb,
              const float* __restrict__ bv, void* __restrict__ Vt,
              const unsigned short* __restrict__ kbn, const unsigned short* __restrict__ wkb,
              const float* __restrict__ bk, void* __restrict__ Khd,
              const int* __restrict__ map, const int* __restrict__ cnt)
{
    __shared__ unsigned short sm[24576];
    const int id = blockIdx.x;
    if (id < 512)       gemm_core<1, false>(id,       qb,  wqb, bq, alpha_q, Qh,  sm, nullptr, nullptr);
    else if (id < 1024) gemm_core<2, true >(id & 511, vb,  wvb, bv, 1.0f,    Vt,  sm, map, cnt);
    else                gemm_core<1, true >(id & 511, kbn, wkb, bk, 1.0f,    Khd, sm, map, cnt);
}

// fused Q+V projections (fallback small-ws path, r15 schedule)
__global__ __launch_bounds__(256)
void gemm_qv(const unsigned short* __restrict__ qb, const unsigned short* __restrict__ wqb,
             const float* __restrict__ bq, float alpha_q, void* __restrict__ Qh,
             const unsigned short* __restrict__ vb, const unsigned short* __restrict__ wvb,
             const float* __restrict__ bv, void* __restrict__ Vt,
             const int* __restrict__ map, const int* __restrict__ cnt)
{
    __shared__ unsigned short sm[24576];
    const int id = blockIdx.x, sub = id & 511;
    if (id < 512) gemm_core<1, false>(sub, qb, wqb, bq, alpha_q, Qh, sm, nullptr, nullptr);
    else          gemm_core<2, true >(sub, vb, wvb, bv, 1.0f,   Vt, sm, map, cnt);
}

template<int OUT_MODE, bool GATHER>
__global__ __launch_bounds__(256)
void gemm_one(const unsigned short* __restrict__ A, const unsigned short* __restrict__ Wb,
              const float* __restrict__ bias, float alpha, void* __restrict__ outp,
              const int* __restrict__ map, const int* __restrict__ cnt)
{
    __shared__ unsigned short sm[24576];
    gemm_core<OUT_MODE, GATHER>(blockIdx.x, A, Wb, bias, alpha, outp, sm, map, cnt);
}

// ---------------- attention (compacted K/V, staged; + fused Wo conversion) ----------------
// bh < 32: per block 64 q-rows (4 waves x 16), KVBLK=64, K/V double-buffered in LDS
// with async global_load_lds prefetch (hides L2 latency -- r14 proved direct global
// fragment reads are latency-bound). Swapped QK^T (mfma(K,Q)): lane holds
// P[k=tt*16+quad*4+r][q=lr]. Block recounts cnt from masks; iterates ceil(cnt/64)
// tiles; pad tail masked via additive -1e5 in MFMA accumulator (exp2 -> +0).
// bh == 32: 32 blocks convert Wo (fp32->bf16, 1M elems) into wob concurrently.
__global__ __launch_bounds__(256)
void attn_kernel(const unsigned short* __restrict__ Qh, const unsigned short* __restrict__ Kh,
                 const unsigned short* __restrict__ Vt, const int* __restrict__ kpm,
                 const int* __restrict__ am, unsigned short* __restrict__ ctx,
                 const float* __restrict__ Wo, unsigned short* __restrict__ wob)
{
    const int bh = blockIdx.y;
    const int tid = threadIdx.x;
    if (bh >= 32) {
        // ---- Wo conversion: 32 blocks x 16 sweeps x 2048 elems ----
        const int base = (blockIdx.x * 256 + tid) * 8;   // 0..65535 step 8
        for (int i = base; i < (1 << 20); i += 32 * 256 * 8) {
            const float4 a = *(const float4*)(Wo + i);
            const float4 b = *(const float4*)(Wo + i + 4);
            ushort4 lo, hi;
            lo.x = f2bf(a.x); lo.y = f2bf(a.y); lo.z = f2bf(a.z); lo.w = f2bf(a.w);
            hi.x = f2bf(b.x); hi.y = f2bf(b.y); hi.z = f2bf(b.z); hi.w = f2bf(b.w);
            *(ushort4*)(wob + i) = lo;
            *(ushort4*)(wob + i + 4) = hi;
        }
        return;
    }

    const int qb = blockIdx.x, b = bh >> 4, h = bh & 15;
    const int q0 = qb * 64;
    const int lane = tid & 63, wave = tid >> 6;
    const int lr = lane & 15, quad = lane >> 4;

    __shared__ unsigned short Ks[2][64 * 64];
    __shared__ unsigned short Vs[2][64 * 64];
    __shared__ int wred[4];

    // recount unmasked columns for this batch (matches scan's predicate)
    {
        int c = 0;
        const int mb = b * 2048 + tid * 8;
#pragma unroll
        for (int e = 0; e < 8; ++e)
            c += (kpm[mb + e] | am[mb + e]) ? 0 : 1;
#pragma unroll
        for (int off = 32; off > 0; off >>= 1)
            c += __shfl_xor(c, off, 64);
        if (lane == 0) wred[wave] = c;
    }
    __syncthreads();
    const int cntb = wred[0] + wred[1] + wred[2] + wred[3];
    const int nits = (cntb > 0) ? ((cntb + 63) >> 6) : 1;

    const unsigned short* Kbh = Kh + (size_t)bh * 2048 * 64;
    const unsigned short* Vbh = Vt + (size_t)bh * 64 * 2048;

    const int lr3 = lane >> 3;
    const int qcs = (lane & 7) ^ lr3;

    auto stage = [&](int buf, int k0) {
#pragma unroll
        for (int n = 0; n < 2; ++n) {
            const int W = wave + n * 4;
            const int r = W * 8 + lr3;
            GLL16(Kbh + (size_t)(k0 + r) * 64 + qcs * 8, &Ks[buf][W * 512]);
            GLL16(Vbh + (size_t)r * 2048 + k0 + qcs * 8, &Vs[buf][W * 512]);
        }
    };

    const unsigned short* Qbase = Qh + ((size_t)bh * 2048 + q0 + wave * 16 + lr) * 64 + quad * 8;
    const short8 qf0 = *(const short8*)Qbase;
    const short8 qf1 = *(const short8*)(Qbase + 32);

    short8 onesA;
#pragma unroll
    for (int j = 0; j < 8; j++) onesA[j] = (short)0x3F80;

    f32x4 o[4];
    f32x4 lacc = (f32x4){0.f, 0.f, 0.f, 0.f};
#pragma unroll
    for (int nt = 0; nt < 4; nt++) o[nt] = (f32x4){0.f, 0.f, 0.f, 0.f};

    const int srcA = (quad & 1) * 32 + lr;
    const int srcB = srcA + 16;

    // Precompute swizzled LDS fragment offsets (loop-invariant; keep in VGPRs).
    int koff[2][2][2], voff[2][4];
#pragma unroll
    for (int s32 = 0; s32 < 2; ++s32) {
#pragma unroll
        for (int tt = 0; tt < 2; ++tt) {
            const int kk = (s32 * 2 + tt) * 16 + lr;
            koff[s32][tt][0] = (kk * 8 + (quad ^ (kk & 7))) * 8;
            koff[s32][tt][1] = (kk * 8 + ((quad + 4) ^ (kk & 7))) * 8;
        }
#pragma unroll
        for (int nt = 0; nt < 4; ++nt) {
            const int d = nt * 16 + lr;
            const int qc = s32 * 4 + quad;
            voff[s32][nt] = (d * 8 + (qc ^ (d & 7))) * 8;
        }
    }

    auto tile = [&](const unsigned short* __restrict__ Kb,
                    const unsigned short* __restrict__ Vb, int k0) {
#pragma unroll
        for (int s32 = 0; s32 < 2; ++s32) {
            unsigned int pk[2][2];
#pragma unroll
            for (int tt = 0; tt < 2; ++tt) {
                const short8 kf0 = *(const short8*)&Kb[koff[s32][tt][0]];
                const short8 kf1 = *(const short8*)&Kb[koff[s32][tt][1]];
                f32x4 z;
                if (k0 + 64 <= cntb) {        // uniform branch: tile fully valid
                    z = (f32x4){0.f, 0.f, 0.f, 0.f};
                } else {                       // last tile: mask padded columns
                    const int jb = k0 + (s32 * 2 + tt) * 16 + quad * 4;
#pragma unroll
                    for (int r = 0; r < 4; ++r)
                        z[r] = (jb + r < cntb) ? 0.f : -1e5f;
                }
                z = MFMA16(kf0, qf0, z);
                z = MFMA16(kf1, qf1, z);
                const float p0 = __builtin_amdgcn_exp2f(z[0]);
                const float p1 = __builtin_amdgcn_exp2f(z[1]);
                const float p2 = __builtin_amdgcn_exp2f(z[2]);
                const float p3 = __builtin_amdgcn_exp2f(z[3]);
                pk[tt][0] = ((unsigned)f2bf(p1) << 16) | f2bf(p0);
                pk[tt][1] = ((unsigned)f2bf(p3) << 16) | f2bf(p2);
            }
            const int a0 = __shfl((int)pk[0][0], srcA, 64);
            const int a1 = __shfl((int)pk[0][1], srcA, 64);
            const int a2 = __shfl((int)pk[0][0], srcB, 64);
            const int a3 = __shfl((int)pk[0][1], srcB, 64);
            const int c0 = __shfl((int)pk[1][0], srcA, 64);
            const int c1 = __shfl((int)pk[1][1], srcA, 64);
            const int c2 = __shfl((int)pk[1][0], srcB, 64);
            const int c3 = __shfl((int)pk[1][1], srcB, 64);
            const bool hi = quad >= 2;
            union { int32x4 i; short8 s; } u;
            u.i = (int32x4){hi ? c0 : a0, hi ? c1 : a1, hi ? c2 : a2, hi ? c3 : a3};
            const short8 pb = u.s;

            lacc = MFMA16(onesA, pb, lacc);
#pragma unroll
            for (int nt = 0; nt < 4; ++nt) {
                const short8 vf = *(const short8*)&Vb[voff[s32][nt]];
                o[nt] = MFMA16(vf, pb, o[nt]);
            }
        }
    };

    stage(0, 0);

    for (int it = 0; it < nits; ++it) {
        __syncthreads();
        if (it + 1 < nits) stage((it + 1) & 1, (it + 1) * 64);
        // duplicate body per buffer so LDS base is a compile-time immediate
        if (it & 1) tile(Ks[1], Vs[1], it * 64);
        else        tile(Ks[0], Vs[0], it * 64);
    }

    const float linv = 1.f / lacc[0];
    const int srow = q0 + wave * 16 + lr;
#pragma unroll
    for (int nt = 0; nt < 4; ++nt) {
        ushort4 pk4;
        pk4.x = f2bf(o[nt][0] * linv);
        pk4.y = f2bf(o[nt][1] * linv);
        pk4.z = f2bf(o[nt][2] * linv);
        pk4.w = f2bf(o[nt][3] * linv);
        *(ushort4*)&ctx[((size_t)(b * 2048 + srow)) * 1024 + h * 64 + nt * 16 + quad * 4] = pk4;
    }
}

extern "C" void kernel_launch(void* const* d_in, const int* in_sizes, int n_in,
                              void* d_out, int out_size, void* d_ws, size_t ws_size,
                              hipStream_t stream)
{
    const float* query = (const float*)d_in[0];
    const float* key_  = (const float*)d_in[1];
    const float* value = (const float*)d_in[2];
    const int* kpm     = (const int*)d_in[3];
    const int* am      = (const int*)d_in[4];
    const float* Wq = (const float*)d_in[6];
    const float* bq = (const float*)d_in[7];
    const float* Wk = (const float*)d_in[8];
    const float* bk = (const float*)d_in[9];
    const float* Wv = (const float*)d_in[10];
    const float* bv = (const float*)d_in[11];
    const float* Wo = (const float*)d_in[12];
    const float* bo = (const float*)d_in[13];

    unsigned short* ws16 = (unsigned short*)d_ws;
    unsigned short* Qh  = ws16;                         // 4M elems
    unsigned short* kbn = ws16 + (1u << 22);            // 4M: bf16 key input
    unsigned short* wob = ws16 + (1u << 22);            // 1M: reuses kbn after proj-GEMMs
    unsigned short* Vt  = ws16 + (2u << 22);            // 4M
    unsigned short* ctx = ws16 + 3 * (1u << 22);        // 4M (attn output)
    unsigned short* wqb = ctx;                          // 1M (dead before attn)
    unsigned short* wvb = ctx + (1u << 20);             // 1M
    unsigned short* wkb = ctx + (2u << 20);             // 1M
    int* map = (int*)(ctx + (3u << 20));                // 2x2048 ints (dead before attn writes ctx)
    int* cnt = map + 4096;                              // 2 ints

    unsigned short* ob  = (unsigned short*)d_out;       // 8M ushorts of scratch
    unsigned short* qb  = ob;                           // 4M
    unsigned short* vb  = ob + (1u << 22);              // 4M

    const dim3 blk(256);
    const float alpha_q = 0.125f * 1.4426950408889634f; // fold 1/sqrt(64) and log2(e) into Q

    conv_scan<<<dim3(2048, 7), blk, 0, stream>>>(
        query, qb,  1 << 22,
        value, vb,  1 << 22,
        key_,  kbn, 1 << 22,
        Wq,    wqb, 1 << 20,
        Wv,    wvb, 1 << 20,
        Wk,    wkb, 1 << 20,
        kpm, am, map, cnt);

    if (ws_size >= ((size_t)40 << 20)) {
        // big-ws path: K output at ws+32MB, all three projections in ONE launch
        unsigned short* Khd2 = ws16 + (1u << 24);       // ushort idx 16M = byte 32MB
        gemm_qvk<<<1536, blk, 0, stream>>>(qb, wqb, bq, alpha_q, (void*)Qh,
                                           vb, wvb, bv, (void*)Vt,
                                           kbn, wkb, bk, (void*)Khd2, map, cnt);
        attn_kernel<<<dim3(32, 33), blk, 0, stream>>>(Qh, Khd2, Vt, kpm, am, ctx, Wo, wob);
    } else {
        // fallback (r15 schedule): K-GEMM separate, output in d_out scratch
        unsigned short* Khd = ob;                       // reuses qb after QV-GEMM
        gemm_qv<<<1024, blk, 0, stream>>>(qb, wqb, bq, alpha_q, (void*)Qh,
                                          vb, wvb, bv, (void*)Vt, map, cnt);
        gemm_one<1, true><<<512, blk, 0, stream>>>(kbn, wkb, bk, 1.0f, (void*)Khd, map, cnt);
        attn_kernel<<<dim3(32, 33), blk, 0, stream>>>(Qh, Khd, Vt, kpm, am, ctx, Wo, wob);
    }
    gemm_one<0, false><<<512, blk, 0, stream>>>(ctx, wob, bo, 1.0f, d_out, nullptr, nullptr);
}